// Round 1
// baseline (691.099 us; speedup 1.0000x reference)
//
#include <hip/hip_runtime.h>
#include <cmath>

#define T_DIM 1024
#define B_DIM 8
#define C_DIM 256
#define H_DIM 8
#define D_DIM 32
#define F_DIM 512

// ---------------------------------------------------------------------------
// LayerNorm: one wave per row of C=256 (float4 per lane), 4 rows per block.
// var = E[x^2] - E[x]^2 (matches jnp.var), eps=1e-5.
// ---------------------------------------------------------------------------
__global__ __launch_bounds__(256) void ln_kernel(const float* __restrict__ x,
                                                 const float* __restrict__ g,
                                                 const float* __restrict__ bta,
                                                 float* __restrict__ y)
{
    int row  = blockIdx.x * 4 + (threadIdx.x >> 6);
    int lane = threadIdx.x & 63;
    const float4* xr = (const float4*)(x + (size_t)row * C_DIM);
    float4 v = xr[lane];
    float s  = v.x + v.y + v.z + v.w;
    float ss = v.x * v.x + v.y * v.y + v.z * v.z + v.w * v.w;
#pragma unroll
    for (int off = 1; off < 64; off <<= 1) {
        s  += __shfl_xor(s, off);
        ss += __shfl_xor(ss, off);
    }
    float mu   = s * (1.0f / C_DIM);
    float var  = ss * (1.0f / C_DIM) - mu * mu;
    float rstd = rsqrtf(var + 1e-5f);
    float4 gv = ((const float4*)g)[lane];
    float4 bv = ((const float4*)bta)[lane];
    float4 o;
    o.x = (v.x - mu) * rstd * gv.x + bv.x;
    o.y = (v.y - mu) * rstd * gv.y + bv.y;
    o.z = (v.z - mu) * rstd * gv.z + bv.z;
    o.w = (v.w - mu) * rstd * gv.w + bv.w;
    ((float4*)(y + (size_t)row * C_DIM))[lane] = o;
}

// ---------------------------------------------------------------------------
// GEMM: out[m,n] = sum_k A[m,k] * W[n,k] + bias[n]  (both operands K-contiguous)
// EPI: 0 = plain store, 1 = exact GELU, 2 = add residual R[m,n].
// 64x64 tile, BK=16, 256 threads, 4x4 outputs/thread, padded LDS.
// Assumes M%64==0, N%64==0, K%16==0 (true for all shapes here).
// ---------------------------------------------------------------------------
template<int EPI>
__global__ __launch_bounds__(256) void gemm_bt(const float* __restrict__ A,
                                               const float* __restrict__ W,
                                               const float* __restrict__ bias,
                                               const float* __restrict__ R,
                                               float* __restrict__ out,
                                               int M, int N, int K)
{
    __shared__ float As[64][17];
    __shared__ float Ws[64][17];
    int tid = threadIdx.x;
    int tx = tid & 15, ty = tid >> 4;
    int row0 = blockIdx.y * 64, col0 = blockIdx.x * 64;
    float acc[4][4] = {};
    for (int k0 = 0; k0 < K; k0 += 16) {
#pragma unroll
        for (int i = 0; i < 4; i++) {
            int idx = tid + i * 256;
            int r = idx >> 4, c = idx & 15;
            As[r][c] = A[(size_t)(row0 + r) * K + k0 + c];
            Ws[r][c] = W[(size_t)(col0 + r) * K + k0 + c];
        }
        __syncthreads();
#pragma unroll
        for (int kk = 0; kk < 16; kk++) {
            float a[4], b[4];
#pragma unroll
            for (int i = 0; i < 4; i++) a[i] = As[ty * 4 + i][kk];
#pragma unroll
            for (int j = 0; j < 4; j++) b[j] = Ws[tx * 4 + j][kk];
#pragma unroll
            for (int i = 0; i < 4; i++)
#pragma unroll
                for (int j = 0; j < 4; j++) acc[i][j] += a[i] * b[j];
        }
        __syncthreads();
    }
#pragma unroll
    for (int i = 0; i < 4; i++) {
#pragma unroll
        for (int j = 0; j < 4; j++) {
            int r = row0 + ty * 4 + i;
            int c = col0 + tx * 4 + j;
            float v = acc[i][j] + bias[c];
            if (EPI == 1) {
                v = 0.5f * v * (1.0f + erff(v * 0.70710678118654752f));
            } else if (EPI == 2) {
                v += R[(size_t)r * N + c];
            }
            out[(size_t)r * N + c] = v;
        }
    }
}

// ---------------------------------------------------------------------------
// Fused flash attention with dense edge bias.
// Grid: (T/64, B*H). Block: 256 threads = 64 q-rows x 4 key-splits.
// Thread (r, s) handles q-row t = bx*64+r, keys kk ≡ s (mod 4).
// Online softmax (rare-rescale), K/V tiles (128x32) staged in LDS (pad 33).
// Split-merge via 4-lane __shfl_xor. Output written as [T,B,C] scratch.
// ---------------------------------------------------------------------------
__global__ __launch_bounds__(256) void attn_kernel(const float* __restrict__ qkv,
                                                   const float* __restrict__ bias,
                                                   const unsigned char* __restrict__ mask,
                                                   float* __restrict__ o)
{
    __shared__ float k_s[128][33];
    __shared__ float v_s[128][33];
    __shared__ unsigned char m_s[128];

    int tid = threadIdx.x;
    int s = tid & 3;      // key split
    int r = tid >> 2;     // local q row 0..63
    int bh = blockIdx.y;  // b*H + h
    int b = bh >> 3, hh = bh & 7;
    int t = blockIdx.x * 64 + r;

    const float scale = 0.17677669529663687f;  // 1/sqrt(32)
    const float* qrow = qkv + ((size_t)t * B_DIM + b) * (3 * C_DIM) + hh * D_DIM;
    float q[D_DIM];
#pragma unroll
    for (int d = 0; d < D_DIM; d++) q[d] = qrow[d] * scale;

    float m = -INFINITY, l = 0.0f;
    float acc[D_DIM] = {};
    const float* brow = bias + ((size_t)bh * T_DIM + t) * T_DIM;

    for (int k0 = 0; k0 < T_DIM; k0 += 128) {
        // stage K,V tiles: 128 rows x 32 dims, 16 elements per thread
#pragma unroll
        for (int i = 0; i < 16; i++) {
            int idx = tid + i * 256;
            int kt = idx >> 5, d = idx & 31;
            size_t base = ((size_t)(k0 + kt) * B_DIM + b) * (3 * C_DIM) + hh * D_DIM + d;
            k_s[kt][d] = qkv[base + C_DIM];
            v_s[kt][d] = qkv[base + 2 * C_DIM];
        }
        if (tid < 128) m_s[tid] = mask[(size_t)b * T_DIM + k0 + tid];
        __syncthreads();

#pragma unroll 4
        for (int i = 0; i < 32; i++) {
            int kk = s + i * 4;
            float sc = 0.0f;
#pragma unroll
            for (int d = 0; d < D_DIM; d++) sc += q[d] * k_s[kk][d];
            sc += brow[k0 + kk];
            if (m_s[kk]) sc = -1e9f;
            if (sc > m) {
                float corr = __expf(m - sc);
                l *= corr;
#pragma unroll
                for (int d = 0; d < D_DIM; d++) acc[d] *= corr;
                m = sc;
            }
            float p = __expf(sc - m);
            l += p;
#pragma unroll
            for (int d = 0; d < D_DIM; d++) acc[d] += p * v_s[kk][d];
        }
        __syncthreads();
    }

    // merge the 4 splits (lanes r*4 + {0,1,2,3} are in the same wave)
    float m2 = fmaxf(m, __shfl_xor(m, 1));
    m2 = fmaxf(m2, __shfl_xor(m2, 2));
    float corr = __expf(m - m2);
    l *= corr;
    l += __shfl_xor(l, 1);
    l += __shfl_xor(l, 2);
    float inv_l = 1.0f / l;
#pragma unroll
    for (int d = 0; d < D_DIM; d++) {
        float a = acc[d] * corr;
        a += __shfl_xor(a, 1);
        a += __shfl_xor(a, 2);
        acc[d] = a * inv_l;
    }
    // each split-thread writes 8 of the 32 dims
    float* orow = o + ((size_t)t * B_DIM + b) * C_DIM + hh * D_DIM;
#pragma unroll
    for (int j = 0; j < 8; j++) orow[s * 8 + j] = acc[s * 8 + j];
}

// ---------------------------------------------------------------------------
extern "C" void kernel_launch(void* const* d_in, const int* in_sizes, int n_in,
                              void* d_out, int out_size, void* d_ws, size_t ws_size,
                              hipStream_t stream)
{
    const float* x            = (const float*)d_in[0];
    const unsigned char* mask = (const unsigned char*)d_in[1];
    const float* bias         = (const float*)d_in[2];
    const float* ln1g         = (const float*)d_in[3];
    const float* ln1b         = (const float*)d_in[4];
    const float* ln2g         = (const float*)d_in[5];
    const float* ln2b         = (const float*)d_in[6];
    const float* wqkv         = (const float*)d_in[7];
    const float* bqkv         = (const float*)d_in[8];
    const float* wo           = (const float*)d_in[9];
    const float* bo           = (const float*)d_in[10];
    const float* w1           = (const float*)d_in[11];
    const float* b1           = (const float*)d_in[12];
    const float* w2           = (const float*)d_in[13];
    const float* b2           = (const float*)d_in[14];
    float* out = (float*)d_out;
    float* ws  = (float*)d_ws;

    // workspace layout (floats): y(8MB) qkv(24MB) o(8MB) x1(8MB) h(16MB) = 64MB
    float* y   = ws;
    float* qkv = ws + 2097152;
    float* o   = ws + 8388608;
    float* x1  = ws + 10485760;
    float* h   = ws + 12582912;

    const int M = T_DIM * B_DIM;  // 8192 tokens

    // 1) y = LN1(x)
    ln_kernel<<<M / 4, 256, 0, stream>>>(x, ln1g, ln1b, y);
    // 2) qkv = y @ Wqkv^T + bqkv   [8192, 768]
    gemm_bt<0><<<dim3(768 / 64, M / 64), 256, 0, stream>>>(y, wqkv, bqkv, nullptr, qkv, M, 3 * C_DIM, C_DIM);
    // 3) o = softmax(q k^T * scale + edge_bias, mask) v   -> [T,B,C]
    attn_kernel<<<dim3(T_DIM / 64, B_DIM * H_DIM), 256, 0, stream>>>(qkv, bias, mask, o);
    // 4) x1 = x + o @ Wo^T + bo
    gemm_bt<2><<<dim3(256 / 64, M / 64), 256, 0, stream>>>(o, wo, bo, x, x1, M, C_DIM, C_DIM);
    // 5) y = LN2(x1)
    ln_kernel<<<M / 4, 256, 0, stream>>>(x1, ln2g, ln2b, y);
    // 6) h = gelu(y @ W1^T + b1)   [8192, 512]
    gemm_bt<1><<<dim3(512 / 64, M / 64), 256, 0, stream>>>(y, w1, b1, nullptr, h, M, F_DIM, C_DIM);
    // 7) out = x1 + h @ W2^T + b2
    gemm_bt<2><<<dim3(256 / 64, M / 64), 256, 0, stream>>>(h, w2, b2, x1, out, M, C_DIM, F_DIM);
}

// Round 2
// 139.439 us; speedup vs baseline: 4.9563x; 4.9563x over previous
//
#include <hip/hip_runtime.h>
#include <hip/hip_bf16.h>
#include <cmath>

#define T_DIM 1024
#define B_DIM 8
#define C_DIM 256
#define H_DIM 8
#define D_DIM 32
#define F_DIM 512

typedef __attribute__((ext_vector_type(4))) float f32x4;
typedef __attribute__((ext_vector_type(8))) short bf16x8;

static __device__ __forceinline__ unsigned short f2bf(float f) {
    union { float f; unsigned u; } v; v.f = f;
    unsigned r = v.u + 0x7fff + ((v.u >> 16) & 1);
    return (unsigned short)(r >> 16);
}

// ---------------------------------------------------------------------------
// Convert the 4 weight matrices f32 -> bf16 into one contiguous ws region.
// segments: wqkv [0,196608) wo [196608,262144) w1 [262144,393216) w2 [...,524288)
// ---------------------------------------------------------------------------
__global__ __launch_bounds__(256) void convert_weights(const float* __restrict__ wqkv,
                                                       const float* __restrict__ wo,
                                                       const float* __restrict__ w1,
                                                       const float* __restrict__ w2,
                                                       unsigned short* __restrict__ dst)
{
    int e = blockIdx.x * 256 + threadIdx.x;
    const float* src; int off;
    if (e < 196608)      { src = wqkv; off = 0; }
    else if (e < 262144) { src = wo;   off = 196608; }
    else if (e < 393216) { src = w1;   off = 262144; }
    else                 { src = w2;   off = 393216; }
    dst[e] = f2bf(src[e - off]);
}

// ---------------------------------------------------------------------------
// LayerNorm: one wave per row of C=256, float4 per lane, bf16 output.
// ---------------------------------------------------------------------------
__global__ __launch_bounds__(256) void ln_bf16(const float* __restrict__ x,
                                               const float* __restrict__ g,
                                               const float* __restrict__ bta,
                                               unsigned short* __restrict__ y)
{
    int row  = blockIdx.x * 4 + (threadIdx.x >> 6);
    int lane = threadIdx.x & 63;
    float4 v = ((const float4*)(x + (size_t)row * C_DIM))[lane];
    float s  = v.x + v.y + v.z + v.w;
    float ss = v.x * v.x + v.y * v.y + v.z * v.z + v.w * v.w;
#pragma unroll
    for (int off = 1; off < 64; off <<= 1) {
        s  += __shfl_xor(s, off);
        ss += __shfl_xor(ss, off);
    }
    float mu   = s * (1.0f / C_DIM);
    float var  = ss * (1.0f / C_DIM) - mu * mu;
    float rstd = rsqrtf(var + 1e-5f);
    float4 gv = ((const float4*)g)[lane];
    float4 bv = ((const float4*)bta)[lane];
    ushort4 o;
    o.x = f2bf((v.x - mu) * rstd * gv.x + bv.x);
    o.y = f2bf((v.y - mu) * rstd * gv.y + bv.y);
    o.z = f2bf((v.z - mu) * rstd * gv.z + bv.z);
    o.w = f2bf((v.w - mu) * rstd * gv.w + bv.w);
    ((ushort4*)(y + (size_t)row * C_DIM))[lane] = o;
}

// ---------------------------------------------------------------------------
// bf16 MFMA GEMM: out[m,n] = A[m,k] * W[n,k] + bias[n]  (K-contiguous operands)
// Block: 256 thr = 4 waves; tile BM=128 (wave: 32 rows), BN=64, BK=32.
// EPI: 0 = store bf16, 1 = exact GELU -> bf16, 2 = +R residual -> f32.
// ---------------------------------------------------------------------------
template<int EPI>
__global__ __launch_bounds__(256) void gemm_mfma(const unsigned short* __restrict__ A,
                                                 const unsigned short* __restrict__ W,
                                                 const float* __restrict__ bias,
                                                 const float* __restrict__ R,
                                                 void* __restrict__ outv,
                                                 int N, int K)
{
    __shared__ unsigned short A_s[128][40];
    __shared__ unsigned short W_s[64][40];
    int tid  = threadIdx.x;
    int lane = tid & 63;
    int wv   = tid >> 6;
    int l15  = lane & 15, lg = lane >> 4;
    int row0 = blockIdx.y * 128;
    int col0 = blockIdx.x * 64;

    f32x4 acc[2][4] = {};
    for (int k0 = 0; k0 < K; k0 += 32) {
#pragma unroll
        for (int i = 0; i < 8; i++) {
            int p = tid + i * 256;
            int m = p >> 4, dp = (p & 15) * 2;
            *(uint32_t*)&A_s[m][dp] = *(const uint32_t*)(A + (size_t)(row0 + m) * K + k0 + dp);
        }
#pragma unroll
        for (int i = 0; i < 4; i++) {
            int p = tid + i * 256;
            int n = p >> 4, dp = (p & 15) * 2;
            *(uint32_t*)&W_s[n][dp] = *(const uint32_t*)(W + (size_t)(col0 + n) * K + k0 + dp);
        }
        __syncthreads();
        bf16x8 af[2], wf[4];
#pragma unroll
        for (int mb = 0; mb < 2; mb++)
            af[mb] = *(const bf16x8*)&A_s[wv * 32 + mb * 16 + l15][lg * 8];
#pragma unroll
        for (int nb = 0; nb < 4; nb++)
            wf[nb] = *(const bf16x8*)&W_s[nb * 16 + l15][lg * 8];
#pragma unroll
        for (int mb = 0; mb < 2; mb++)
#pragma unroll
            for (int nb = 0; nb < 4; nb++)
                acc[mb][nb] = __builtin_amdgcn_mfma_f32_16x16x32_bf16(af[mb], wf[nb], acc[mb][nb], 0, 0, 0);
        __syncthreads();
    }
    // epilogue: D layout col = l15 (n), row = lg*4 + r (m)
#pragma unroll
    for (int nb = 0; nb < 4; nb++) {
        int c = col0 + nb * 16 + l15;
        float bv = bias[c];
#pragma unroll
        for (int mb = 0; mb < 2; mb++) {
#pragma unroll
            for (int r = 0; r < 4; r++) {
                int rowm = row0 + wv * 32 + mb * 16 + lg * 4 + r;
                float v = acc[mb][nb][r] + bv;
                if (EPI == 1) v = 0.5f * v * (1.0f + erff(v * 0.70710678118654752f));
                if (EPI == 2) {
                    v += R[(size_t)rowm * N + c];
                    ((float*)outv)[(size_t)rowm * N + c] = v;
                } else {
                    ((unsigned short*)outv)[(size_t)rowm * N + c] = f2bf(v);
                }
            }
        }
    }
}

// ---------------------------------------------------------------------------
// MFMA flash attention with dense edge bias.
// Grid (T/64, B*H); block 256 = 4 waves, wave owns 16 q-rows.
// S^T = K @ Q^T  (mfma 16x16x32): lane holds q = l&15, kv = (l>>4)*4 + reg.
// Online softmax; P -> per-wave LDS strip -> B-frag; O^T += V^T @ P^T.
// ---------------------------------------------------------------------------
__global__ __launch_bounds__(256) void attn_mfma(const unsigned short* __restrict__ qkv,
                                                 const float* __restrict__ bias,
                                                 const unsigned char* __restrict__ mask,
                                                 unsigned short* __restrict__ o)
{
    __shared__ unsigned short K_s[64][40];    // [kv][d]
    __shared__ unsigned short Vt_s[32][72];   // [d][kv]
    __shared__ unsigned short P_s[4][16][72]; // per-wave [q][kv]
    __shared__ float bias_s[64][68];          // [q][kv]
    __shared__ unsigned char m_s[64];

    int tid  = threadIdx.x;
    int lane = tid & 63;
    int wv   = tid >> 6;
    int l15  = lane & 15, lg = lane >> 4;
    int bh = blockIdx.y, b = bh >> 3, hh = bh & 7;
    int q0 = blockIdx.x * 64;
    int qw = q0 + wv * 16;
    const float scale = 0.17677669529663687f;

    // Q fragment (B-operand): q = l15, d = lg*8 + i  -> 16B contiguous
    bf16x8 qf = *(const bf16x8*)(qkv + ((size_t)(qw + l15) * B_DIM + b) * 768 + hh * 32 + lg * 8);

    float m_run = -INFINITY, l_run = 0.0f;
    f32x4 oacc[2] = {};  // O^T: q = l15, d = db*16 + lg*4 + reg

    for (int k0 = 0; k0 < T_DIM; k0 += 64) {
        // ---- stage K[64x32], V^T[32x64] (bf16), bias[64x64] (f32), mask ----
#pragma unroll
        for (int i = 0; i < 4; i++) {
            int p = tid + i * 256;              // 1024 d-pairs
            int kv = p >> 4, dp = (p & 15) * 2;
            const unsigned short* src = qkv + ((size_t)(k0 + kv) * B_DIM + b) * 768 + hh * 32;
            uint32_t kk = *(const uint32_t*)(src + 256 + dp);
            uint32_t vv = *(const uint32_t*)(src + 512 + dp);
            *(uint32_t*)&K_s[kv][dp] = kk;
            Vt_s[dp][kv]     = (unsigned short)(vv & 0xffff);
            Vt_s[dp + 1][kv] = (unsigned short)(vv >> 16);
        }
#pragma unroll
        for (int i = 0; i < 4; i++) {
            int p = tid + i * 256;              // 1024 f32x4 tiles: 64q x 64kv
            int q = p >> 4, c4 = (p & 15) * 4;
            *(f32x4*)&bias_s[q][c4] =
                *(const f32x4*)(bias + ((size_t)bh * T_DIM + q0 + q) * T_DIM + k0 + c4);
        }
        if (tid < 64) m_s[tid] = mask[b * T_DIM + k0 + tid];
        __syncthreads();

        // ---- S^T = K @ Q^T over 4 kv-blocks ----
        float sv[4][4];
        float tmax = -INFINITY;
#pragma unroll
        for (int kb = 0; kb < 4; kb++) {
            bf16x8 kf = *(const bf16x8*)&K_s[kb * 16 + l15][lg * 8];
            f32x4 z = {0.0f, 0.0f, 0.0f, 0.0f};
            f32x4 sc = __builtin_amdgcn_mfma_f32_16x16x32_bf16(kf, qf, z, 0, 0, 0);
            f32x4 bv = *(const f32x4*)&bias_s[wv * 16 + l15][kb * 16 + lg * 4];
            uint32_t mw = *(const uint32_t*)&m_s[kb * 16 + lg * 4];
#pragma unroll
            for (int r = 0; r < 4; r++) {
                float s = sc[r] * scale + bv[r];
                if ((mw >> (8 * r)) & 0xff) s = -1e9f;
                sv[kb][r] = s;
                tmax = fmaxf(tmax, s);
            }
        }
        tmax = fmaxf(tmax, __shfl_xor(tmax, 16));
        tmax = fmaxf(tmax, __shfl_xor(tmax, 32));
        float m_new = fmaxf(m_run, tmax);
        float corr = __expf(m_run - m_new);
        m_run = m_new;

        float ls = 0.0f;
#pragma unroll
        for (int kb = 0; kb < 4; kb++) {
            float p0 = __expf(sv[kb][0] - m_new);
            float p1 = __expf(sv[kb][1] - m_new);
            float p2 = __expf(sv[kb][2] - m_new);
            float p3 = __expf(sv[kb][3] - m_new);
            ls += (p0 + p1) + (p2 + p3);
            uint2 pw;
            pw.x = (uint32_t)f2bf(p0) | ((uint32_t)f2bf(p1) << 16);
            pw.y = (uint32_t)f2bf(p2) | ((uint32_t)f2bf(p3) << 16);
            *(uint2*)&P_s[wv][l15][kb * 16 + lg * 4] = pw;   // same-wave produce
        }
        ls += __shfl_xor(ls, 16);
        ls += __shfl_xor(ls, 32);
        l_run = l_run * corr + ls;
#pragma unroll
        for (int db = 0; db < 2; db++)
#pragma unroll
            for (int r = 0; r < 4; r++) oacc[db][r] *= corr;

        // ---- O^T += V^T @ P^T : 2 kv-halves x 2 d-blocks ----
#pragma unroll
        for (int h = 0; h < 2; h++) {
            bf16x8 pf = *(const bf16x8*)&P_s[wv][l15][h * 32 + lg * 8];  // same-wave consume
#pragma unroll
            for (int db = 0; db < 2; db++) {
                bf16x8 vf = *(const bf16x8*)&Vt_s[db * 16 + l15][h * 32 + lg * 8];
                oacc[db] = __builtin_amdgcn_mfma_f32_16x16x32_bf16(vf, pf, oacc[db], 0, 0, 0);
            }
        }
        __syncthreads();
    }

    // normalize, transpose via LDS (reuse bias_s rows: per-wave disjoint), store bf16
    float inv = 1.0f / l_run;
#pragma unroll
    for (int db = 0; db < 2; db++)
#pragma unroll
        for (int r = 0; r < 4; r++)
            bias_s[wv * 16 + l15][db * 16 + lg * 4 + r] = oacc[db][r] * inv;
    __syncthreads();
#pragma unroll
    for (int i = 0; i < 8; i++) {
        int p = tid + i * 256;      // 2048 = 64q x 32d
        int lq = p >> 5, d = p & 31;
        o[((size_t)(q0 + lq) * B_DIM + b) * C_DIM + hh * 32 + d] = f2bf(bias_s[lq][d]);
    }
}

// ---------------------------------------------------------------------------
extern "C" void kernel_launch(void* const* d_in, const int* in_sizes, int n_in,
                              void* d_out, int out_size, void* d_ws, size_t ws_size,
                              hipStream_t stream)
{
    const float* x            = (const float*)d_in[0];
    const unsigned char* mask = (const unsigned char*)d_in[1];
    const float* bias         = (const float*)d_in[2];
    const float* ln1g         = (const float*)d_in[3];
    const float* ln1b         = (const float*)d_in[4];
    const float* ln2g         = (const float*)d_in[5];
    const float* ln2b         = (const float*)d_in[6];
    const float* wqkv         = (const float*)d_in[7];
    const float* bqkv         = (const float*)d_in[8];
    const float* wo           = (const float*)d_in[9];
    const float* bo           = (const float*)d_in[10];
    const float* w1           = (const float*)d_in[11];
    const float* b1           = (const float*)d_in[12];
    const float* w2           = (const float*)d_in[13];
    const float* b2           = (const float*)d_in[14];
    float* out = (float*)d_out;
    char* ws   = (char*)d_ws;

    // ws layout (bytes)
    unsigned short* wbf     = (unsigned short*)ws;                     // 1 MB (4 weights)
    unsigned short* wqkv_bf = wbf;
    unsigned short* wo_bf   = wbf + 196608;
    unsigned short* w1_bf   = wbf + 262144;
    unsigned short* w2_bf   = wbf + 393216;
    unsigned short* y_bf    = (unsigned short*)(ws + (1u << 20));      // 4 MB
    unsigned short* qkv_bf  = (unsigned short*)(ws + 5u * (1u << 20)); // 12 MB
    unsigned short* o_bf    = (unsigned short*)(ws + 17u * (1u << 20)); // 4 MB
    float*          x1      = (float*)(ws + 21u * (1u << 20));         // 8 MB
    unsigned short* h_bf    = (unsigned short*)(ws + 29u * (1u << 20)); // 8 MB

    const int M = T_DIM * B_DIM;  // 8192

    convert_weights<<<2048, 256, 0, stream>>>(wqkv, wo, w1, w2, wbf);
    ln_bf16<<<M / 4, 256, 0, stream>>>(x, ln1g, ln1b, y_bf);
    gemm_mfma<0><<<dim3(768 / 64, M / 128), 256, 0, stream>>>(y_bf, wqkv_bf, bqkv, nullptr, qkv_bf, 768, 256);
    attn_mfma<<<dim3(T_DIM / 64, B_DIM * H_DIM), 256, 0, stream>>>(qkv_bf, bias, mask, o_bf);
    gemm_mfma<2><<<dim3(256 / 64, M / 128), 256, 0, stream>>>(o_bf, wo_bf, bo, x, x1, 256, 256);
    ln_bf16<<<M / 4, 256, 0, stream>>>(x1, ln2g, ln2b, y_bf);
    gemm_mfma<1><<<dim3(512 / 64, M / 128), 256, 0, stream>>>(y_bf, w1_bf, b1, nullptr, h_bf, 512, 256);
    gemm_mfma<2><<<dim3(256 / 64, M / 128), 256, 0, stream>>>(h_bf, w2_bf, b2, x1, out, 256, 512);
}

// Round 3
// 138.559 us; speedup vs baseline: 4.9878x; 1.0064x over previous
//
#include <hip/hip_runtime.h>
#include <hip/hip_bf16.h>
#include <cmath>

#define T_DIM 1024
#define B_DIM 8
#define C_DIM 256
#define H_DIM 8
#define D_DIM 32
#define F_DIM 512

typedef __attribute__((ext_vector_type(4))) float f32x4;
typedef __attribute__((ext_vector_type(8))) short bf16x8;

static __device__ __forceinline__ unsigned short f2bf(float f) {
    union { float f; unsigned u; } v; v.f = f;
    unsigned r = v.u + 0x7fff + ((v.u >> 16) & 1);
    return (unsigned short)(r >> 16);
}

// async global->LDS, 16B per lane; LDS dest = wave-uniform base + lane*16
static __device__ __forceinline__ void gload_lds16(const void* g, void* l) {
    __builtin_amdgcn_global_load_lds(
        (const __attribute__((address_space(1))) unsigned int*)g,
        (__attribute__((address_space(3))) unsigned int*)l,
        16, 0, 0);
}

// ---------------------------------------------------------------------------
// Convert the 4 weight matrices f32 -> bf16 into one contiguous ws region.
// ---------------------------------------------------------------------------
__global__ __launch_bounds__(256) void convert_weights(const float* __restrict__ wqkv,
                                                       const float* __restrict__ wo,
                                                       const float* __restrict__ w1,
                                                       const float* __restrict__ w2,
                                                       unsigned short* __restrict__ dst)
{
    int e = blockIdx.x * 256 + threadIdx.x;
    const float* src; int off;
    if (e < 196608)      { src = wqkv; off = 0; }
    else if (e < 262144) { src = wo;   off = 196608; }
    else if (e < 393216) { src = w1;   off = 262144; }
    else                 { src = w2;   off = 393216; }
    dst[e] = f2bf(src[e - off]);
}

// ---------------------------------------------------------------------------
// LayerNorm: one wave per row of C=256, float4 per lane, bf16 output.
// ---------------------------------------------------------------------------
__global__ __launch_bounds__(256) void ln_bf16(const float* __restrict__ x,
                                               const float* __restrict__ g,
                                               const float* __restrict__ bta,
                                               unsigned short* __restrict__ y)
{
    int row  = blockIdx.x * 4 + (threadIdx.x >> 6);
    int lane = threadIdx.x & 63;
    float4 v = ((const float4*)(x + (size_t)row * C_DIM))[lane];
    float s  = v.x + v.y + v.z + v.w;
    float ss = v.x * v.x + v.y * v.y + v.z * v.z + v.w * v.w;
#pragma unroll
    for (int off = 1; off < 64; off <<= 1) {
        s  += __shfl_xor(s, off);
        ss += __shfl_xor(ss, off);
    }
    float mu   = s * (1.0f / C_DIM);
    float var  = ss * (1.0f / C_DIM) - mu * mu;
    float rstd = rsqrtf(var + 1e-5f);
    float4 gv = ((const float4*)g)[lane];
    float4 bv = ((const float4*)bta)[lane];
    ushort4 o;
    o.x = f2bf((v.x - mu) * rstd * gv.x + bv.x);
    o.y = f2bf((v.y - mu) * rstd * gv.y + bv.y);
    o.z = f2bf((v.z - mu) * rstd * gv.z + bv.z);
    o.w = f2bf((v.w - mu) * rstd * gv.w + bv.w);
    ((ushort4*)(y + (size_t)row * C_DIM))[lane] = o;
}

// ---------------------------------------------------------------------------
// bf16 MFMA GEMM: out[m,n] = A[m,k] * W[n,k] + bias[n]
// BM=128, BN=64, BK=64, 4 waves. global_load_lds(16B) staging, linear LDS,
// XOR swizzle: LDS unit (row,c') holds global unit c'^(row&7); ds_read applies
// the same XOR -> bank-conflict-free b128 reads.
// EPI: 0 = store bf16, 1 = exact GELU -> bf16, 2 = +R residual -> f32.
// ---------------------------------------------------------------------------
template<int EPI>
__global__ __launch_bounds__(256) void gemm_mfma(const unsigned short* __restrict__ A,
                                                 const unsigned short* __restrict__ W,
                                                 const float* __restrict__ bias,
                                                 const float* __restrict__ R,
                                                 void* __restrict__ outv,
                                                 int N, int K)
{
    __shared__ __align__(16) unsigned short A_s[128 * 64];
    __shared__ __align__(16) unsigned short W_s[64 * 64];
    int tid  = threadIdx.x;
    int lane = tid & 63;
    int wv   = tid >> 6;
    int l15  = lane & 15, lg = lane >> 4;
    int row0 = blockIdx.y * 128;
    int col0 = blockIdx.x * 64;

    f32x4 acc[2][4] = {};
    for (int k0 = 0; k0 < K; k0 += 64) {
#pragma unroll
        for (int i = 0; i < 4; i++) {                 // A tile: 128x64 bf16
            int u = (wv * 4 + i) * 64 + lane;
            int r = u >> 3, c = u & 7;
            gload_lds16(A + (size_t)(row0 + r) * K + k0 + ((c ^ (r & 7)) * 8),
                        &A_s[(size_t)(wv * 4 + i) * 512]);
        }
#pragma unroll
        for (int j = 0; j < 2; j++) {                 // W tile: 64x64 bf16
            int u = (wv * 2 + j) * 64 + lane;
            int r = u >> 3, c = u & 7;
            gload_lds16(W + (size_t)(col0 + r) * K + k0 + ((c ^ (r & 7)) * 8),
                        &W_s[(size_t)(wv * 2 + j) * 512]);
        }
        __syncthreads();
#pragma unroll
        for (int kk = 0; kk < 2; kk++) {
            bf16x8 af[2], wf[4];
#pragma unroll
            for (int mb = 0; mb < 2; mb++) {
                int rowa = wv * 32 + mb * 16 + l15;
                af[mb] = *(const bf16x8*)&A_s[rowa * 64 + (((kk * 4 + lg) ^ (l15 & 7)) * 8)];
            }
#pragma unroll
            for (int nb = 0; nb < 4; nb++) {
                int roww = nb * 16 + l15;
                wf[nb] = *(const bf16x8*)&W_s[roww * 64 + (((kk * 4 + lg) ^ (l15 & 7)) * 8)];
            }
#pragma unroll
            for (int mb = 0; mb < 2; mb++)
#pragma unroll
                for (int nb = 0; nb < 4; nb++)
                    acc[mb][nb] = __builtin_amdgcn_mfma_f32_16x16x32_bf16(af[mb], wf[nb], acc[mb][nb], 0, 0, 0);
        }
        __syncthreads();
    }
#pragma unroll
    for (int nb = 0; nb < 4; nb++) {
        int c = col0 + nb * 16 + l15;
        float bv = bias[c];
#pragma unroll
        for (int mb = 0; mb < 2; mb++) {
#pragma unroll
            for (int r = 0; r < 4; r++) {
                int rowm = row0 + wv * 32 + mb * 16 + lg * 4 + r;
                float v = acc[mb][nb][r] + bv;
                if (EPI == 1) v = 0.5f * v * (1.0f + erff(v * 0.70710678118654752f));
                if (EPI == 2) {
                    v += R[(size_t)rowm * N + c];
                    ((float*)outv)[(size_t)rowm * N + c] = v;
                } else {
                    ((unsigned short*)outv)[(size_t)rowm * N + c] = f2bf(v);
                }
            }
        }
    }
}

// ---------------------------------------------------------------------------
// MFMA flash attention with dense edge bias.
// Grid (T/64, B*H); block 256 = 4 waves, wave owns 16 q-rows.
// Bias loaded straight to registers in accumulator layout (read-once data).
// K tile via global_load_lds(16B) with XOR swizzle (c ^= row&3).
// O^T stored directly from registers (ushort4), no transpose LDS.
// ---------------------------------------------------------------------------
__global__ __launch_bounds__(256) void attn_mfma(const unsigned short* __restrict__ qkv,
                                                 const float* __restrict__ bias,
                                                 const unsigned char* __restrict__ mask,
                                                 unsigned short* __restrict__ o)
{
    __shared__ __align__(16) unsigned short K_s[64 * 32];  // linear, swizzled
    __shared__ unsigned short Vt_s[32][72];                // [d][kv]
    __shared__ unsigned short P_s[4][16][72];              // per-wave [q][kv]
    __shared__ unsigned char m_s[64];

    int tid  = threadIdx.x;
    int lane = tid & 63;
    int wv   = tid >> 6;
    int l15  = lane & 15, lg = lane >> 4;
    int bh = blockIdx.y, b = bh >> 3, hh = bh & 7;
    int q0 = blockIdx.x * 64;
    int qw = q0 + wv * 16;
    const float scale = 0.17677669529663687f;  // 1/sqrt(32)

    // Q fragment (B-operand): q = l15, d = lg*8..+7
    bf16x8 qf = *(const bf16x8*)(qkv + ((size_t)(qw + l15) * B_DIM + b) * 768 + hh * 32 + lg * 8);

    // K staging: one gload_lds per wave covers rows wv*16..wv*16+15 (4 units/row)
    int krow = wv * 16 + (lane >> 2);
    int kc   = lane & 3;
    int kswz = (kc ^ (krow & 3)) * 8;
    // per-lane read offset for kf (loop-invariant part)
    const unsigned short* kfp = &K_s[l15 * 32 + ((lg ^ (l15 & 3)) * 8)];

    const float* bptr = bias + ((size_t)bh * T_DIM + q0 + wv * 16 + l15) * T_DIM + lg * 4;

    float m_run = -INFINITY, l_run = 0.0f;
    f32x4 oacc[2] = {};  // lane: q = l15, d = db*16 + lg*4 + r

    for (int k0 = 0; k0 < T_DIM; k0 += 64) {
        // bias for this iter: 4x f32x4 in accumulator layout (read-once, no LDS)
        f32x4 bb0 = *(const f32x4*)(bptr + k0);
        f32x4 bb1 = *(const f32x4*)(bptr + k0 + 16);
        f32x4 bb2 = *(const f32x4*)(bptr + k0 + 32);
        f32x4 bb3 = *(const f32x4*)(bptr + k0 + 48);
        // K tile 64x32 bf16 via global_load_lds
        gload_lds16(qkv + ((size_t)(k0 + krow) * B_DIM + b) * 768 + 256 + hh * 32 + kswz,
                    &K_s[(size_t)wv * 512]);
        // V tile -> transposed LDS (reg-staged)
#pragma unroll
        for (int i = 0; i < 4; i++) {
            int p = tid + i * 256;
            int kv = p >> 4, dp = (p & 15) * 2;
            uint32_t vv = *(const uint32_t*)(qkv + ((size_t)(k0 + kv) * B_DIM + b) * 768 + 512 + hh * 32 + dp);
            Vt_s[dp][kv]     = (unsigned short)(vv & 0xffff);
            Vt_s[dp + 1][kv] = (unsigned short)(vv >> 16);
        }
        if (tid < 64) m_s[tid] = mask[b * T_DIM + k0 + tid];
        __syncthreads();

        // ---- S^T = K @ Q^T over 4 kv-blocks ----
        float sv[4][4];
        float tmax = -INFINITY;
        const f32x4 bb[4] = {bb0, bb1, bb2, bb3};
#pragma unroll
        for (int kb = 0; kb < 4; kb++) {
            bf16x8 kf = *(const bf16x8*)(kfp + kb * 512);
            f32x4 z = {0.0f, 0.0f, 0.0f, 0.0f};
            f32x4 sc = __builtin_amdgcn_mfma_f32_16x16x32_bf16(kf, qf, z, 0, 0, 0);
            uint32_t mw = *(const uint32_t*)&m_s[kb * 16 + lg * 4];
#pragma unroll
            for (int r = 0; r < 4; r++) {
                float s = sc[r] * scale + bb[kb][r];
                if ((mw >> (8 * r)) & 0xff) s = -1e9f;
                sv[kb][r] = s;
                tmax = fmaxf(tmax, s);
            }
        }
        tmax = fmaxf(tmax, __shfl_xor(tmax, 16));
        tmax = fmaxf(tmax, __shfl_xor(tmax, 32));
        float m_new = fmaxf(m_run, tmax);
        float corr = __expf(m_run - m_new);
        m_run = m_new;

        float ls = 0.0f;
#pragma unroll
        for (int kb = 0; kb < 4; kb++) {
            float p0 = __expf(sv[kb][0] - m_new);
            float p1 = __expf(sv[kb][1] - m_new);
            float p2 = __expf(sv[kb][2] - m_new);
            float p3 = __expf(sv[kb][3] - m_new);
            ls += (p0 + p1) + (p2 + p3);
            uint2 pw;
            pw.x = (uint32_t)f2bf(p0) | ((uint32_t)f2bf(p1) << 16);
            pw.y = (uint32_t)f2bf(p2) | ((uint32_t)f2bf(p3) << 16);
            *(uint2*)&P_s[wv][l15][kb * 16 + lg * 4] = pw;   // same-wave produce
        }
        ls += __shfl_xor(ls, 16);
        ls += __shfl_xor(ls, 32);
        l_run = l_run * corr + ls;
#pragma unroll
        for (int db = 0; db < 2; db++)
#pragma unroll
            for (int r = 0; r < 4; r++) oacc[db][r] *= corr;

        // ---- O^T += V^T @ P^T ----
#pragma unroll
        for (int h = 0; h < 2; h++) {
            bf16x8 pf = *(const bf16x8*)&P_s[wv][l15][h * 32 + lg * 8];
#pragma unroll
            for (int db = 0; db < 2; db++) {
                bf16x8 vf = *(const bf16x8*)&Vt_s[db * 16 + l15][h * 32 + lg * 8];
                oacc[db] = __builtin_amdgcn_mfma_f32_16x16x32_bf16(vf, pf, oacc[db], 0, 0, 0);
            }
        }
        __syncthreads();
    }

    // direct store: token = qw+l15, dims d = db*16 + lg*4 + r (4 contiguous)
    float inv = 1.0f / l_run;
#pragma unroll
    for (int db = 0; db < 2; db++) {
        ushort4 ov;
        ov.x = f2bf(oacc[db][0] * inv);
        ov.y = f2bf(oacc[db][1] * inv);
        ov.z = f2bf(oacc[db][2] * inv);
        ov.w = f2bf(oacc[db][3] * inv);
        *(ushort4*)(o + ((size_t)(qw + l15) * B_DIM + b) * C_DIM + hh * 32 + db * 16 + lg * 4) = ov;
    }
}

// ---------------------------------------------------------------------------
extern "C" void kernel_launch(void* const* d_in, const int* in_sizes, int n_in,
                              void* d_out, int out_size, void* d_ws, size_t ws_size,
                              hipStream_t stream)
{
    const float* x            = (const float*)d_in[0];
    const unsigned char* mask = (const unsigned char*)d_in[1];
    const float* bias         = (const float*)d_in[2];
    const float* ln1g         = (const float*)d_in[3];
    const float* ln1b         = (const float*)d_in[4];
    const float* ln2g         = (const float*)d_in[5];
    const float* ln2b         = (const float*)d_in[6];
    const float* wqkv         = (const float*)d_in[7];
    const float* bqkv         = (const float*)d_in[8];
    const float* wo           = (const float*)d_in[9];
    const float* bo           = (const float*)d_in[10];
    const float* w1           = (const float*)d_in[11];
    const float* b1           = (const float*)d_in[12];
    const float* w2           = (const float*)d_in[13];
    const float* b2           = (const float*)d_in[14];
    float* out = (float*)d_out;
    char* ws   = (char*)d_ws;

    unsigned short* wbf     = (unsigned short*)ws;                      // 1 MB
    unsigned short* wqkv_bf = wbf;
    unsigned short* wo_bf   = wbf + 196608;
    unsigned short* w1_bf   = wbf + 262144;
    unsigned short* w2_bf   = wbf + 393216;
    unsigned short* y_bf    = (unsigned short*)(ws + (1u << 20));       // 4 MB
    unsigned short* qkv_bf  = (unsigned short*)(ws + 5u * (1u << 20));  // 12 MB
    unsigned short* o_bf    = (unsigned short*)(ws + 17u * (1u << 20)); // 4 MB
    float*          x1      = (float*)(ws + 21u * (1u << 20));          // 8 MB
    unsigned short* h_bf    = (unsigned short*)(ws + 29u * (1u << 20)); // 8 MB

    const int M = T_DIM * B_DIM;  // 8192

    convert_weights<<<2048, 256, 0, stream>>>(wqkv, wo, w1, w2, wbf);
    ln_bf16<<<M / 4, 256, 0, stream>>>(x, ln1g, ln1b, y_bf);
    gemm_mfma<0><<<dim3(768 / 64, M / 128), 256, 0, stream>>>(y_bf, wqkv_bf, bqkv, nullptr, qkv_bf, 768, 256);
    attn_mfma<<<dim3(T_DIM / 64, B_DIM * H_DIM), 256, 0, stream>>>(qkv_bf, bias, mask, o_bf);
    gemm_mfma<2><<<dim3(256 / 64, M / 128), 256, 0, stream>>>(o_bf, wo_bf, bo, x, x1, 256, 256);
    ln_bf16<<<M / 4, 256, 0, stream>>>(x1, ln2g, ln2b, y_bf);
    gemm_mfma<1><<<dim3(512 / 64, M / 128), 256, 0, stream>>>(y_bf, w1_bf, b1, nullptr, h_bf, 512, 256);
    gemm_mfma<2><<<dim3(256 / 64, M / 128), 256, 0, stream>>>(h_bf, w2_bf, b2, x1, out, 256, 512);
}